// Round 1
// baseline (119.405 us; speedup 1.0000x reference)
//
#include <hip/hip_runtime.h>

#define NEGF (-1e30f)

// Problem constants (from setup_inputs: B=8, T=128, U=64, V=1024)
#define B_   8
#define T_   128
#define U_   64
#define U1_  65
#define V_   1024
#define PAD_ 66                 // padded row stride for lpb/lpl (diagonal LDS reads hit distinct banks)
#define ROWS_ (B_*T_*U1_)       // 66560
#define WS_PER_ (T_*PAD_)       // 8448 floats per batch per array

__device__ __forceinline__ float logaddexpf_(float a, float b) {
  float m = fmaxf(a, b);
  float d = fminf(a, b) - m;          // d <= 0 always; -inf-ish -> exp underflows to 0
  return m + log1pf(__expf(d));
}

// ---------------------------------------------------------------------------
// K1: one wave per (b,t,u) row of V=1024. Compute logsumexp; emit
//     lp_blank[b][t][u] and masked lp_label[b][t][u] into padded workspace.
// ---------------------------------------------------------------------------
__global__ __launch_bounds__(256) void k1_logsoftmax(
    const float* __restrict__ acts, const int* __restrict__ labels,
    const int* __restrict__ label_lens,
    float* __restrict__ lpb, float* __restrict__ lpl) {
  const int lane = threadIdx.x & 63;
  const int wv   = threadIdx.x >> 6;
  const int row  = blockIdx.x * 4 + wv;            // grid is exact: rows/4 blocks
  const float* __restrict__ p = acts + (size_t)row * V_;

  float4 v0 = *(const float4*)(p + 0   + lane * 4);
  float4 v1 = *(const float4*)(p + 256 + lane * 4);
  float4 v2 = *(const float4*)(p + 512 + lane * 4);
  float4 v3 = *(const float4*)(p + 768 + lane * 4);

  float m = fmaxf(fmaxf(fmaxf(v0.x, v0.y), fmaxf(v0.z, v0.w)),
            fmaxf(fmaxf(fmaxf(v1.x, v1.y), fmaxf(v1.z, v1.w)),
            fmaxf(fmaxf(fmaxf(v2.x, v2.y), fmaxf(v2.z, v2.w)),
                  fmaxf(fmaxf(v3.x, v3.y), fmaxf(v3.z, v3.w)))));
  #pragma unroll
  for (int o = 32; o; o >>= 1) m = fmaxf(m, __shfl_xor(m, o, 64));

  float s = __expf(v0.x - m) + __expf(v0.y - m) + __expf(v0.z - m) + __expf(v0.w - m)
          + __expf(v1.x - m) + __expf(v1.y - m) + __expf(v1.z - m) + __expf(v1.w - m)
          + __expf(v2.x - m) + __expf(v2.y - m) + __expf(v2.z - m) + __expf(v2.w - m)
          + __expf(v3.x - m) + __expf(v3.y - m) + __expf(v3.z - m) + __expf(v3.w - m);
  #pragma unroll
  for (int o = 32; o; o >>= 1) s += __shfl_xor(s, o, 64);

  float lse = m + __logf(s);                       // s >= 1 (max element contributes 1)

  if (lane == 0) {
    int b   = row / (T_ * U1_);
    int rem = row - b * (T_ * U1_);
    int t   = rem / U1_;
    int u   = rem - t * U1_;
    size_t base = ((size_t)b * T_ + t) * PAD_;
    lpb[base + u] = v0.x - lse;                    // element 0 lives in lane 0's v0.x
    if (u < U_) {
      float val = NEGF;
      if (u < label_lens[b]) {
        int lab = labels[b * U_ + u];              // in [1, V)
        val = p[lab] - lse;                        // row is hot in L1/L2
      }
      lpl[base + u] = val;
    }
  }
}

// ---------------------------------------------------------------------------
// K2: per-batch alpha lattice via anti-diagonals. Block = 256 threads: all
//     stage LDS; wave 0 (64 lanes) runs the DP (lane l owns column u=l+1,
//     column u=0 is a prefix sum). No barriers inside the diagonal loop.
// ---------------------------------------------------------------------------
__global__ __launch_bounds__(256) void k2_alpha(
    const float* __restrict__ lpb, const float* __restrict__ lpl,
    const int* __restrict__ act_lens, const int* __restrict__ label_lens,
    float* __restrict__ costs) {
  __shared__ float lpb_s[T_ * PAD_];
  __shared__ float lpl_s[T_ * PAD_];
  __shared__ float alpha0_s[T_];
  const int b = blockIdx.x;

  {  // flat float4 copy (WS_PER_ is a multiple of 4; batch base is 16B aligned)
    const float4* s1 = (const float4*)(lpb + (size_t)b * WS_PER_);
    const float4* s2 = (const float4*)(lpl + (size_t)b * WS_PER_);
    float4* d1 = (float4*)lpb_s;
    float4* d2 = (float4*)lpl_s;
    for (int i = threadIdx.x; i < WS_PER_ / 4; i += 256) { d1[i] = s1[i]; d2[i] = s2[i]; }
  }
  __syncthreads();
  if (threadIdx.x >= 64) return;

  const int l  = threadIdx.x;
  const int tl = act_lens[b] - 1;
  const int ll = label_lens[b];

  // alpha[t][0] = sum_{j<t} lpb[j][0]  (exclusive prefix over T=128, two chunks)
  float x0 = lpb_s[l * PAD_];
  float x1 = lpb_s[(l + 64) * PAD_];
  float s0 = x0;
  #pragma unroll
  for (int o = 1; o < 64; o <<= 1) { float tmp = __shfl_up(s0, o, 64); if (l >= o) s0 += tmp; }
  float tot0 = __shfl(s0, 63, 64);
  float s1v = x1;
  #pragma unroll
  for (int o = 1; o < 64; o <<= 1) { float tmp = __shfl_up(s1v, o, 64); if (l >= o) s1v += tmp; }
  alpha0_s[l]      = s0 - x0;
  alpha0_s[l + 64] = tot0 + s1v - x1;

  // diagonal sweep: at diagonal d, lane l computes cell (t = d-u, u = l+1)
  const int u = l + 1;
  float a    = NEGF;
  float fin  = 0.0f;
  bool  have = false;
  for (int d = 1; d <= T_ - 1 + U_; ++d) {
    int  t     = d - u;
    bool valid = (t >= 0) && (t < T_);
    float left = __shfl_up(a, 1, 64);              // alpha[t][u-1] from lane l-1
    int tc  = t < 0 ? 0 : (t > T_ - 1 ? T_ - 1 : t);
    if (l == 0) left = alpha0_s[tc];               // u-1 == 0 column
    int tm1 = tc > 0 ? tc - 1 : 0;
    float blank = (t >= 1 && t < T_) ? (a + lpb_s[tm1 * PAD_ + u]) : NEGF;
    float label = left + lpl_s[tc * PAD_ + (u - 1)];
    float anew  = logaddexpf_(blank, label);       // t==0 row: logaddexp(NEG, label) == ref
    a = valid ? anew : NEGF;
    if (valid && t == tl && u == ll) { fin = a; have = true; }
  }
  if (have)              costs[b] = -(fin + lpb_s[tl * PAD_ + ll]);
  if (l == 0 && ll == 0) costs[b] = -(alpha0_s[tl] + lpb_s[tl * PAD_]);
}

// ---------------------------------------------------------------------------
// K3: deterministic scalar sum of the 8 per-batch costs.
// ---------------------------------------------------------------------------
__global__ void k3_sum(const float* __restrict__ costs, float* __restrict__ out) {
  if (threadIdx.x == 0) {
    float s = 0.0f;
    #pragma unroll
    for (int i = 0; i < B_; ++i) s += costs[i];
    out[0] = s;
  }
}

extern "C" void kernel_launch(void* const* d_in, const int* in_sizes, int n_in,
                              void* d_out, int out_size, void* d_ws, size_t ws_size,
                              hipStream_t stream) {
  const float* acts       = (const float*)d_in[0];
  const int*   labels     = (const int*)d_in[1];
  const int*   act_lens   = (const int*)d_in[2];
  const int*   label_lens = (const int*)d_in[3];

  float* lpb   = (float*)d_ws;                       // B*T*PAD floats
  float* lpl   = lpb + (size_t)B_ * WS_PER_;         // B*T*PAD floats
  float* costs = lpl + (size_t)B_ * WS_PER_;         // B floats

  k1_logsoftmax<<<ROWS_ / 4, 256, 0, stream>>>(acts, labels, label_lens, lpb, lpl);
  k2_alpha<<<B_, 256, 0, stream>>>(lpb, lpl, act_lens, label_lens, costs);
  k3_sum<<<1, 64, 0, stream>>>(costs, (float*)d_out);
}

// Round 2
// 75.855 us; speedup vs baseline: 1.5741x; 1.5741x over previous
//
#include <hip/hip_runtime.h>

#define NEGF (-1e30f)

// Problem constants (from setup_inputs: B=8, T=128, U=64, V=1024)
#define B_   8
#define T_   128
#define U_   64
#define U1_  65
#define V_   1024
#define PAD_ 66                 // padded row stride for lpb/lpl
#define ROWS_ (B_*T_*U1_)       // 66560
#define WS_PER_ (T_*PAD_)       // 8448 floats per batch per array

// lane l receives lane l-1's value; lane 0 keeps its own (DPP wave_shr:1).
// Single VALU op vs ds_bpermute's ~35-cycle LDS-pipe round trip.
__device__ __forceinline__ float wave_shr1(float x) {
  return __int_as_float(__builtin_amdgcn_update_dpp(
      __float_as_int(x), __float_as_int(x), 0x138, 0xf, 0xf, 0));
}

// ---------------------------------------------------------------------------
// K1: one wave per (b,t,u) row of V=1024. Compute logsumexp; emit
//     lp_blank[b][t][u] and masked lp_label[b][t][u] into padded workspace.
// ---------------------------------------------------------------------------
__global__ __launch_bounds__(256) void k1_logsoftmax(
    const float* __restrict__ acts, const int* __restrict__ labels,
    const int* __restrict__ label_lens,
    float* __restrict__ lpb, float* __restrict__ lpl, int* __restrict__ cnt) {
  const int lane = threadIdx.x & 63;
  const int wv   = threadIdx.x >> 6;
  const int row  = blockIdx.x * 4 + wv;            // grid is exact: rows/4 blocks

  if (blockIdx.x == 0 && threadIdx.x == 0) *cnt = 0;   // reset K2's completion counter

  // decode indices early so the small dependent loads overlap the big ones
  const int b   = row / (T_ * U1_);
  const int rem = row - b * (T_ * U1_);
  const int t   = rem / U1_;
  const int u   = rem - t * U1_;

  const float* __restrict__ p = acts + (size_t)row * V_;

  // hoisted label-path loads (lane 0 only); overlap with row load + reductions
  int ll_ = 0; float labv = 0.0f;
  if (lane == 0 && u < U_) {
    ll_ = label_lens[b];
    int lab = labels[b * U_ + u];                  // in [1, V)
    labv = p[lab];
  }

  float4 v0 = *(const float4*)(p + 0   + lane * 4);
  float4 v1 = *(const float4*)(p + 256 + lane * 4);
  float4 v2 = *(const float4*)(p + 512 + lane * 4);
  float4 v3 = *(const float4*)(p + 768 + lane * 4);

  float m = fmaxf(fmaxf(fmaxf(v0.x, v0.y), fmaxf(v0.z, v0.w)),
            fmaxf(fmaxf(fmaxf(v1.x, v1.y), fmaxf(v1.z, v1.w)),
            fmaxf(fmaxf(fmaxf(v2.x, v2.y), fmaxf(v2.z, v2.w)),
                  fmaxf(fmaxf(v3.x, v3.y), fmaxf(v3.z, v3.w)))));
  #pragma unroll
  for (int o = 32; o; o >>= 1) m = fmaxf(m, __shfl_xor(m, o, 64));

  float s = __expf(v0.x - m) + __expf(v0.y - m) + __expf(v0.z - m) + __expf(v0.w - m)
          + __expf(v1.x - m) + __expf(v1.y - m) + __expf(v1.z - m) + __expf(v1.w - m)
          + __expf(v2.x - m) + __expf(v2.y - m) + __expf(v2.z - m) + __expf(v2.w - m)
          + __expf(v3.x - m) + __expf(v3.y - m) + __expf(v3.z - m) + __expf(v3.w - m);
  #pragma unroll
  for (int o = 32; o; o >>= 1) s += __shfl_xor(s, o, 64);

  float lse = m + __logf(s);                       // s >= 1 (max element contributes 1)

  if (lane == 0) {
    size_t base = ((size_t)b * T_ + t) * PAD_;
    lpb[base + u] = v0.x - lse;                    // element 0 lives in lane 0's v0.x
    if (u < U_) {
      float val = NEGF;
      if (u < ll_) val = labv - lse;
      lpl[base + u] = val;
    }
  }
}

// ---------------------------------------------------------------------------
// K2: per-batch alpha lattice via anti-diagonals. 256 threads stage LDS;
//     wave 0 runs the DP: lane l owns column u=l+1, column u=0 is a prefix
//     sum. Per-diagonal chain: DPP shift + prefetched LDS operands + fast
//     logaddexp (~50-60 cyc). Last block to finish also writes the sum.
// ---------------------------------------------------------------------------
__global__ __launch_bounds__(256) void k2_alpha(
    const float* __restrict__ lpb, const float* __restrict__ lpl,
    const int* __restrict__ act_lens, const int* __restrict__ label_lens,
    float* __restrict__ costs, int* __restrict__ cnt, float* __restrict__ out) {
  __shared__ float lpb_s[WS_PER_];
  __shared__ float lpl_s[WS_PER_];
  __shared__ float alpha0_s[T_];
  const int b = blockIdx.x;

  {  // flat float4 copy (WS_PER_ multiple of 4; batch base is 16B aligned)
    const float4* s1 = (const float4*)(lpb + (size_t)b * WS_PER_);
    const float4* s2 = (const float4*)(lpl + (size_t)b * WS_PER_);
    float4* d1 = (float4*)lpb_s;
    float4* d2 = (float4*)lpl_s;
    #pragma unroll
    for (int k = 0; k < 9; ++k) {                  // 9*256 >= 2112
      int i = k * 256 + (int)threadIdx.x;
      if (i < WS_PER_ / 4) { d1[i] = s1[i]; d2[i] = s2[i]; }
    }
  }
  __syncthreads();
  if (threadIdx.x >= 64) return;

  const int l  = threadIdx.x;
  const int tl = act_lens[b] - 1;
  const int ll = label_lens[b];

  // alpha[t][0] = sum_{j<t} lpb[j][0]  (exclusive prefix over T=128, two chunks)
  float x0 = lpb_s[l * PAD_];
  float x1 = lpb_s[(l + 64) * PAD_];
  float s0 = x0;
  #pragma unroll
  for (int o = 1; o < 64; o <<= 1) { float tmp = __shfl_up(s0, o, 64); if (l >= o) s0 += tmp; }
  float tot0 = __shfl(s0, 63, 64);
  float s1v = x1;
  #pragma unroll
  for (int o = 1; o < 64; o <<= 1) { float tmp = __shfl_up(s1v, o, 64); if (l >= o) s1v += tmp; }
  alpha0_s[l]      = s0 - x0;
  alpha0_s[l + 64] = tot0 + s1v - x1;

  // diagonal sweep: at diagonal d, lane l computes cell (t = d-u, u = l+1)
  const int u = l + 1;
  float a    = NEGF;
  float fin  = 0.0f;
  bool  have = false;

  // prefetch operands for d = 1
  int   t1  = 1 - u;
  int   tc1 = min(max(t1, 0), T_ - 1);
  int   tm1 = max(tc1 - 1, 0);
  float pb  = lpb_s[tm1 * PAD_ + u];
  float pl  = lpl_s[tc1 * PAD_ + (u - 1)];
  float pa0 = alpha0_s[tc1];

  for (int d = 1; d <= T_ - 1 + U_; ++d) {
    // issue next-diagonal LDS reads first (addresses are induction-only)
    int   tn  = d + 1 - u;
    int   tcn = min(max(tn, 0), T_ - 1);
    int   tmn = max(tcn - 1, 0);
    float nb  = lpb_s[tmn * PAD_ + u];
    float nl  = lpl_s[tcn * PAD_ + (u - 1)];
    float na0 = alpha0_s[tcn];

    int  t     = d - u;
    bool valid = (t >= 0) && (t < T_);
    float left = wave_shr1(a);                     // alpha[t][u-1] from lane l-1
    if (l == 0) left = pa0;                        // u-1 == 0 column
    float blank = (t >= 1 && t < T_) ? (a + pb) : NEGF;
    float label = left + pl;
    float mm = fmaxf(blank, label);
    float dd = fminf(blank, label) - mm;           // <= 0; exp underflows safely
    float anew = mm + __logf(1.0f + __expf(dd));
    a = valid ? anew : NEGF;
    if (valid && t == tl && u == ll) { fin = a; have = true; }

    pb = nb; pl = nl; pa0 = na0;
  }
  if (have)              costs[b] = -(fin + lpb_s[tl * PAD_ + ll]);
  if (l == 0 && ll == 0) costs[b] = -(alpha0_s[tl] + lpb_s[tl * PAD_]);

  // last block to arrive sums the 8 costs (deterministic order, one writer)
  __threadfence();
  if (l == 0) {
    int old = atomicAdd(cnt, 1);
    if (old == B_ - 1) {
      __threadfence();
      volatile const float* vc = costs;
      float s = 0.0f;
      #pragma unroll
      for (int i = 0; i < B_; ++i) s += vc[i];
      out[0] = s;
    }
  }
}

extern "C" void kernel_launch(void* const* d_in, const int* in_sizes, int n_in,
                              void* d_out, int out_size, void* d_ws, size_t ws_size,
                              hipStream_t stream) {
  const float* acts       = (const float*)d_in[0];
  const int*   labels     = (const int*)d_in[1];
  const int*   act_lens   = (const int*)d_in[2];
  const int*   label_lens = (const int*)d_in[3];

  float* lpb   = (float*)d_ws;                       // B*T*PAD floats
  float* lpl   = lpb + (size_t)B_ * WS_PER_;         // B*T*PAD floats
  float* costs = lpl + (size_t)B_ * WS_PER_;         // B floats
  int*   cnt   = (int*)(costs + B_);                 // 1 int

  k1_logsoftmax<<<ROWS_ / 4, 256, 0, stream>>>(acts, labels, label_lens, lpb, lpl, cnt);
  k2_alpha<<<B_, 256, 0, stream>>>(lpb, lpl, act_lens, label_lens, costs, cnt, (float*)d_out);
}